// Round 16
// baseline (271.728 us; speedup 1.0000x reference)
//
#include <hip/hip_runtime.h>

#define N_NODES 100000
#define N_EDGES 1000000
#define IN_DIM 32
#define HID_DIM 64
#define N2 (2 * N_NODES)          // (rel,node) buckets
#define NRANGE 8                  // dst ranges == XCD count
#define RNODES (N_NODES / NRANGE) // 12500
#define ECHUNK 2048               // edges per block-chunk in count/fill

// ============ edge preprocessing: rd[e] = (dst<<1) | rel ============

__global__ __launch_bounds__(256) void k_rd(
    const int* __restrict__ ei, const int* __restrict__ ea,
    int* __restrict__ rd)
{
    int e = blockIdx.x * 256 + threadIdx.x;
    if (e >= N_EDGES) return;
    rd[e] = (ei[N_EDGES + e] << 1) | ea[2 * e + 1];
}

// ============ helpers ============

__device__ __forceinline__ unsigned short f2bf(float f) {
    unsigned u = __float_as_uint(f);
    return (unsigned short)((u + 0x7FFFu + ((u >> 16) & 1u)) >> 16);  // RNE
}

__global__ __launch_bounds__(256) void k_xb(
    const float* __restrict__ x, unsigned short* __restrict__ xb)
{
    int i = blockIdx.x * 256 + threadIdx.x;       // over 800K float4s
    if (i >= N_NODES * IN_DIM / 4) return;
    float4 v = ((const float4*)x)[i];
    ushort4 o;
    o.x = f2bf(v.x); o.y = f2bf(v.y); o.z = f2bf(v.z); o.w = f2bf(v.w);
    ((ushort4*)xb)[i] = o;
}

// ============ CSR build: XCD-local histogram -> scan -> XCD-local fill ============

__global__ __launch_bounds__(256) void k_count(
    const int* __restrict__ rd, int* __restrict__ deg)
{
    int range = blockIdx.x & (NRANGE - 1);
    int chunk = blockIdx.x >> 3;
    int lo = range * RNODES;
    int e0 = chunk * ECHUNK;
    int e1 = min(e0 + ECHUNK, N_EDGES);
    for (int e = e0 + threadIdx.x; e < e1; e += 256) {
        int v = rd[e];
        int dst = v >> 1;
        if ((unsigned)(dst - lo) < (unsigned)RNODES)
            atomicAdd(&deg[(v & 1) * N_NODES + dst], 1);
    }
}

__global__ __launch_bounds__(256) void k_scan_local(
    const int* __restrict__ deg, int* __restrict__ offs, int* __restrict__ bsum)
{
    int t = threadIdx.x;
    int i = blockIdx.x * 256 + t;
    int v = (i < N2) ? deg[i] : 0;
    int lane = t & 63, w = t >> 6;
    int s = v;
#pragma unroll
    for (int off = 1; off < 64; off <<= 1) {
        int u = __shfl_up(s, off);
        if (lane >= off) s += u;
    }
    __shared__ int wsum[4];
    if (lane == 63) wsum[w] = s;
    __syncthreads();
    int add = 0;
    for (int ww = 0; ww < w; ++ww) add += wsum[ww];
    s += add;
    if (i < N2) offs[i] = s - v;
    if (t == 255) bsum[blockIdx.x] = s;
}

__global__ __launch_bounds__(64) void k_scan_blocks(int* __restrict__ bsum, int nblk)
{
    int lane = threadIdx.x;  // single wave
    int carry = 0;
    for (int base = 0; base < nblk; base += 64) {
        int i = base + lane;
        int v = (i < nblk) ? bsum[i] : 0;
        int s = v;
#pragma unroll
        for (int off = 1; off < 64; off <<= 1) {
            int u = __shfl_up(s, off);
            if (lane >= off) s += u;
        }
        if (i < nblk) bsum[i] = carry + s - v;
        carry += __shfl(s, 63);
    }
}

__global__ __launch_bounds__(256) void k_scan_add(
    const int* __restrict__ offs, const int* __restrict__ bsum,
    const int* __restrict__ deg,
    int* __restrict__ cursor, int2* __restrict__ od)
{
    int i = blockIdx.x * 256 + threadIdx.x;
    if (i >= N2) return;
    int o = offs[i] + bsum[i >> 8];
    cursor[i] = o;
    od[i] = make_int2(o, deg[i]);
}

__global__ __launch_bounds__(256) void k_fill(
    const int* __restrict__ rd, const int* __restrict__ ei,
    int* __restrict__ cursor, int* __restrict__ elist)
{
    int range = blockIdx.x & (NRANGE - 1);
    int chunk = blockIdx.x >> 3;
    int lo = range * RNODES;
    int e0 = chunk * ECHUNK;
    int e1 = min(e0 + ECHUNK, N_EDGES);
    for (int e = e0 + threadIdx.x; e < e1; e += 256) {
        int v = rd[e];
        int dst = v >> 1;
        if ((unsigned)(dst - lo) < (unsigned)RNODES) {
            int src = ei[e];
            int pos = atomicAdd(&cursor[(v & 1) * N_NODES + dst], 1);
            elist[pos] = src;
        }
    }
}

// ============ math macros ============
// r15 lesson [HIP-compiler]: writing 12 loads "up front" in source does NOT
// keep them in flight -- the pressure-min scheduler sank each load to its
// use (fgemm2 VGPR_Count=32, depth ~2, VALU 33%, latency-bound 78 us).
// r16 fix: __builtin_amdgcn_sched_barrier(0) between the load cluster and
// the compute -- nothing crosses, so all 12 loads issue together (batched
// vmcnt, ~12-deep MLP). One barrier per kk-iter only (m141 showed pinning
// EVERY instruction regresses). kk loops stay "#pragma unroll 1".

#define MACC4(A, v, m)                \
    A.x = fmaf((v).x, m, A.x);        \
    A.y = fmaf((v).y, m, A.y);        \
    A.z = fmaf((v).z, m, A.z);        \
    A.w = fmaf((v).w, m, A.w);

#define BUNPACK(v_, u) {                           \
    v_.x = __uint_as_float((u).x << 16);           \
    v_.y = __uint_as_float((u).x & 0xFFFF0000u);   \
    v_.z = __uint_as_float((u).y << 16);           \
    v_.w = __uint_as_float((u).y & 0xFFFF0000u);   \
}

#define BMACC4(A, u, m) { float4 v_; BUNPACK(v_, u) MACC4(A, v_, m) }

// 8-wide FMA: acc += dot8(row, w[0..7]) given row as two float4
#define ACC8(acc, vlo, vhi, W)                     \
    acc = fmaf((vlo).x, W##0, acc);                \
    acc = fmaf((vlo).y, W##1, acc);                \
    acc = fmaf((vlo).z, W##2, acc);                \
    acc = fmaf((vlo).w, W##3, acc);                \
    acc = fmaf((vhi).x, W##4, acc);                \
    acc = fmaf((vhi).y, W##5, acc);                \
    acc = fmaf((vhi).z, W##6, acc);                \
    acc = fmaf((vhi).w, W##7, acc);

// unpack uint4 (8 bf16) then 8-wide FMA; temps scoped per row
#define BACC8(acc, u, W) {                                        \
    float4 lo_, hi_;                                              \
    lo_.x = __uint_as_float((u).x << 16);                         \
    lo_.y = __uint_as_float((u).x & 0xFFFF0000u);                 \
    lo_.z = __uint_as_float((u).y << 16);                         \
    lo_.w = __uint_as_float((u).y & 0xFFFF0000u);                 \
    hi_.x = __uint_as_float((u).z << 16);                         \
    hi_.y = __uint_as_float((u).z & 0xFFFF0000u);                 \
    hi_.z = __uint_as_float((u).w << 16);                         \
    hi_.w = __uint_as_float((u).w & 0xFFFF0000u);                 \
    ACC8(acc, lo_, hi_, W)                                        \
}

// ============ gather-mean kernels (subgroup-per-node, no LDS) ============

__global__ __launch_bounds__(512, 8) void k_mean1(
    const unsigned short* __restrict__ xb,   // [N][32] bf16
    const int2* __restrict__ od,
    const int* __restrict__ elist,
    unsigned short* __restrict__ M1)         // [2][N][32] bf16
{
    int tid = threadIdx.x;
    int lane = tid & 63;
    int wv   = __builtin_amdgcn_readfirstlane(tid >> 6);
    int n0   = __builtin_amdgcn_readfirstlane(blockIdx.x * 32 + wv * 4);

    // 8 subgroups of 8 lanes: sub = r*4+i -> (node n0+i, rel r)
    int sub  = lane >> 3;
    int node = n0 + (sub & 3);
    int rel  = sub >> 2;
    int q    = lane & 7;          // feature quad (4 feats, 8B bf16)
    int base = lane & 56;

    int2 o = od[rel * N_NODES + node];
    int off = o.x, d = o.y;
    int erA = (q     < d) ? elist[off + q]     : 0;
    int erB = (8 + q < d) ? elist[off + 8 + q] : 0;

    int dm = d;
    dm = max(dm, __shfl_xor(dm, 8));
    dm = max(dm, __shfl_xor(dm, 16));
    dm = max(dm, __shfl_xor(dm, 32));
    int kend = min(dm, 16);

    float4 A = make_float4(0.f, 0.f, 0.f, 0.f);
    for (int k = 0; k < kend; ++k) {
        int idx = (k < 8) ? __shfl(erA, base + k) : __shfl(erB, base + k - 8);
        uint2 u = *(const uint2*)(xb + (size_t)idx * IN_DIM + q * 4);
        float m = (k < d) ? 1.0f : 0.0f;
        BMACC4(A, u, m)
    }
    if (dm > 16) {                               // rare tail
        for (int k = 16; k < dm; ++k) {
            int idx = 0;
            if (k < d) idx = elist[off + k];
            uint2 u = *(const uint2*)(xb + (size_t)idx * IN_DIM + q * 4);
            float m = (k < d) ? 1.0f : 0.0f;
            BMACC4(A, u, m)
        }
    }
    float inv = 1.0f / fmaxf((float)d, 1.0f);
    ushort4 o4;
    o4.x = f2bf(A.x * inv); o4.y = f2bf(A.y * inv);
    o4.z = f2bf(A.z * inv); o4.w = f2bf(A.w * inv);
    *(ushort4*)(M1 + ((size_t)rel * N_NODES + node) * IN_DIM + q * 4) = o4;
}

__global__ __launch_bounds__(512, 8) void k_mean2(
    const unsigned short* __restrict__ h1b,  // [N][64] bf16
    const int2* __restrict__ od,
    const int* __restrict__ elist,
    unsigned short* __restrict__ M2)         // [2][N][64] bf16
{
    int tid = threadIdx.x;
    int lane = tid & 63;
    int wv   = __builtin_amdgcn_readfirstlane(tid >> 6);
    int n0   = __builtin_amdgcn_readfirstlane(blockIdx.x * 32 + wv * 4);

    // 4 subgroups of 16 lanes: sub -> node n0+sub, both rels
    int sub  = lane >> 4;
    int node = n0 + sub;
    int q    = lane & 15;
    int base = lane & 48;

    int2 o0 = od[node];
    int2 o1 = od[N_NODES + node];
    int d0 = o0.y, d1 = o1.y;
    int er0 = (q < d0) ? elist[o0.x + q] : 0;
    int er1 = (q < d1) ? elist[o1.x + q] : 0;

    int dm = max(d0, d1);
    dm = max(dm, __shfl_xor(dm, 16));
    dm = max(dm, __shfl_xor(dm, 32));
    int kend = min(dm, 16);

    float4 A0 = make_float4(0.f, 0.f, 0.f, 0.f);
    float4 A1 = make_float4(0.f, 0.f, 0.f, 0.f);
    for (int k = 0; k < kend; ++k) {
        int i0 = __shfl(er0, base + k);
        int i1 = __shfl(er1, base + k);
        uint2 u0 = *(const uint2*)(h1b + (size_t)i0 * HID_DIM + q * 4);
        uint2 u1 = *(const uint2*)(h1b + (size_t)i1 * HID_DIM + q * 4);
        float m0 = (k < d0) ? 1.0f : 0.0f;
        float m1 = (k < d1) ? 1.0f : 0.0f;
        BMACC4(A0, u0, m0)
        BMACC4(A1, u1, m1)
    }
    if (dm > 16) {
        for (int k = 16; k < dm; ++k) {
            int i0 = 0, i1 = 0;
            if (k < d0) i0 = elist[o0.x + k];
            if (k < d1) i1 = elist[o1.x + k];
            uint2 u0 = *(const uint2*)(h1b + (size_t)i0 * HID_DIM + q * 4);
            uint2 u1 = *(const uint2*)(h1b + (size_t)i1 * HID_DIM + q * 4);
            float m0 = (k < d0) ? 1.0f : 0.0f;
            float m1 = (k < d1) ? 1.0f : 0.0f;
            BMACC4(A0, u0, m0)
            BMACC4(A1, u1, m1)
        }
    }
    float i0v = 1.0f / fmaxf((float)d0, 1.0f);
    float i1v = 1.0f / fmaxf((float)d1, 1.0f);
    ushort4 w0, w1;
    w0.x = f2bf(A0.x * i0v); w0.y = f2bf(A0.y * i0v);
    w0.z = f2bf(A0.z * i0v); w0.w = f2bf(A0.w * i0v);
    w1.x = f2bf(A1.x * i1v); w1.y = f2bf(A1.y * i1v);
    w1.z = f2bf(A1.z * i1v); w1.w = f2bf(A1.w * i1v);
    *(ushort4*)(M2 + (size_t)node * HID_DIM + q * 4) = w0;
    *(ushort4*)(M2 + ((size_t)N_NODES + node) * HID_DIM + q * 4) = w1;
}

// ============ fused GEMM kernels (8-feature iters, sched_barrier-pinned loads) ============

__global__ __launch_bounds__(512, 4) void k_fgemm1(
    const float* __restrict__ x,       // [N][32] f32 (self, exact)
    const unsigned short* __restrict__ M1,  // [2][N][32] bf16 means
    const float* __restrict__ root1,   // [32][64]
    const float* __restrict__ W1,      // [2][32][64]
    const float* __restrict__ b1,      // [64]
    unsigned short* __restrict__ h1b)  // [N][64] bf16
{
    __shared__ float wR[IN_DIM * HID_DIM];
    __shared__ float w0[IN_DIM * HID_DIM];
    __shared__ float w1s[IN_DIM * HID_DIM];
    int tid = threadIdx.x;
    for (int i = tid; i < IN_DIM * HID_DIM; i += 512) {
        wR[i]  = root1[i];
        w0[i]  = W1[i];
        w1s[i] = W1[IN_DIM * HID_DIM + i];
    }
    __syncthreads();

    int j  = tid & 63;
    int n0 = __builtin_amdgcn_readfirstlane(blockIdx.x * 32 + ((tid >> 6) << 2));
    const float* px = x + (size_t)n0 * IN_DIM;
    const unsigned short* p0 = M1 + (size_t)n0 * IN_DIM;
    const unsigned short* p1 = M1 + ((size_t)N_NODES + n0) * IN_DIM;

    float accR0 = 0, accR1 = 0, accR2 = 0, accR3 = 0;
    float acc00 = 0, acc01 = 0, acc02 = 0, acc03 = 0;
    float acc10 = 0, acc11 = 0, acc12 = 0, acc13 = 0;

#pragma unroll 1
    for (int kk = 0; kk < IN_DIM / 8; ++kk) {   // 4 iters of 8 features
        int kbase = kk * 8;
        float4 x0l = *(const float4*)(px + 0 * IN_DIM + kbase);
        float4 x0h = *(const float4*)(px + 0 * IN_DIM + kbase + 4);
        float4 x1l = *(const float4*)(px + 1 * IN_DIM + kbase);
        float4 x1h = *(const float4*)(px + 1 * IN_DIM + kbase + 4);
        float4 x2l = *(const float4*)(px + 2 * IN_DIM + kbase);
        float4 x2h = *(const float4*)(px + 2 * IN_DIM + kbase + 4);
        float4 x3l = *(const float4*)(px + 3 * IN_DIM + kbase);
        float4 x3h = *(const float4*)(px + 3 * IN_DIM + kbase + 4);
        uint4 a0 = *(const uint4*)(p0 + 0 * IN_DIM + kbase);
        uint4 a1 = *(const uint4*)(p0 + 1 * IN_DIM + kbase);
        uint4 a2 = *(const uint4*)(p0 + 2 * IN_DIM + kbase);
        uint4 a3 = *(const uint4*)(p0 + 3 * IN_DIM + kbase);
        uint4 c0 = *(const uint4*)(p1 + 0 * IN_DIM + kbase);
        uint4 c1 = *(const uint4*)(p1 + 1 * IN_DIM + kbase);
        uint4 c2 = *(const uint4*)(p1 + 2 * IN_DIM + kbase);
        uint4 c3 = *(const uint4*)(p1 + 3 * IN_DIM + kbase);
        // pin: all 16 loads issue before any compute (r15: VGPR=32 showed
        // the scheduler otherwise sinks loads to uses -> depth ~2)
        __builtin_amdgcn_sched_barrier(0);

        int wb_i = kbase * 64 + j;
        float wR_0 = wR[wb_i], wR_1 = wR[wb_i + 64], wR_2 = wR[wb_i + 128], wR_3 = wR[wb_i + 192];
        float wR_4 = wR[wb_i + 256], wR_5 = wR[wb_i + 320], wR_6 = wR[wb_i + 384], wR_7 = wR[wb_i + 448];
        float wA_0 = w0[wb_i], wA_1 = w0[wb_i + 64], wA_2 = w0[wb_i + 128], wA_3 = w0[wb_i + 192];
        float wA_4 = w0[wb_i + 256], wA_5 = w0[wb_i + 320], wA_6 = w0[wb_i + 384], wA_7 = w0[wb_i + 448];
        float wB_0 = w1s[wb_i], wB_1 = w1s[wb_i + 64], wB_2 = w1s[wb_i + 128], wB_3 = w1s[wb_i + 192];
        float wB_4 = w1s[wb_i + 256], wB_5 = w1s[wb_i + 320], wB_6 = w1s[wb_i + 384], wB_7 = w1s[wb_i + 448];

        ACC8(accR0, x0l, x0h, wR_)
        ACC8(accR1, x1l, x1h, wR_)
        ACC8(accR2, x2l, x2h, wR_)
        ACC8(accR3, x3l, x3h, wR_)
        BACC8(acc00, a0, wA_)
        BACC8(acc01, a1, wA_)
        BACC8(acc02, a2, wA_)
        BACC8(acc03, a3, wA_)
        BACC8(acc10, c0, wB_)
        BACC8(acc11, c1, wB_)
        BACC8(acc12, c2, wB_)
        BACC8(acc13, c3, wB_)
    }

    float bj = b1[j];
    h1b[(size_t)(n0 + 0) * HID_DIM + j] = f2bf(fmaxf(accR0 + bj + acc00 + acc10, 0.0f));
    h1b[(size_t)(n0 + 1) * HID_DIM + j] = f2bf(fmaxf(accR1 + bj + acc01 + acc11, 0.0f));
    h1b[(size_t)(n0 + 2) * HID_DIM + j] = f2bf(fmaxf(accR2 + bj + acc02 + acc12, 0.0f));
    h1b[(size_t)(n0 + 3) * HID_DIM + j] = f2bf(fmaxf(accR3 + bj + acc03 + acc13, 0.0f));
}

__global__ __launch_bounds__(512, 4) void k_fgemm2(
    const unsigned short* __restrict__ h1b,  // [N][64] bf16 (self)
    const unsigned short* __restrict__ M2,   // [2][N][64] bf16 means
    const float* __restrict__ root2,   // [64][64] -- global/L1 (LDS 33 KB)
    const float* __restrict__ W2,      // [2][64][64]
    const float* __restrict__ b2,      // [64]
    const float* __restrict__ Wc,      // [64][2]
    const float* __restrict__ bc,      // [2]
    float* __restrict__ out)           // [N][2]
{
    __shared__ float w0[HID_DIM * HID_DIM];
    __shared__ float w1s[HID_DIM * HID_DIM];
    __shared__ float wc[HID_DIM * 2];
    int tid = threadIdx.x;
    for (int i = tid; i < HID_DIM * HID_DIM; i += 512) {
        w0[i]  = W2[i];
        w1s[i] = W2[HID_DIM * HID_DIM + i];
    }
    if (tid < HID_DIM * 2) wc[tid] = Wc[tid];
    __syncthreads();

    int j  = tid & 63;
    int n0 = __builtin_amdgcn_readfirstlane(blockIdx.x * 32 + ((tid >> 6) << 2));
    const unsigned short* px = h1b + (size_t)n0 * HID_DIM;
    const unsigned short* p0 = M2 + (size_t)n0 * HID_DIM;
    const unsigned short* p1 = M2 + ((size_t)N_NODES + n0) * HID_DIM;

    float accR0 = 0, accR1 = 0, accR2 = 0, accR3 = 0;
    float acc00 = 0, acc01 = 0, acc02 = 0, acc03 = 0;
    float acc10 = 0, acc11 = 0, acc12 = 0, acc13 = 0;

#pragma unroll 1
    for (int kk = 0; kk < HID_DIM / 8; ++kk) {   // 8 iters of 8 features
        int kbase = kk * 8;
        uint4 s0 = *(const uint4*)(px + 0 * HID_DIM + kbase);
        uint4 s1 = *(const uint4*)(px + 1 * HID_DIM + kbase);
        uint4 s2 = *(const uint4*)(px + 2 * HID_DIM + kbase);
        uint4 s3 = *(const uint4*)(px + 3 * HID_DIM + kbase);
        uint4 a0 = *(const uint4*)(p0 + 0 * HID_DIM + kbase);
        uint4 a1 = *(const uint4*)(p0 + 1 * HID_DIM + kbase);
        uint4 a2 = *(const uint4*)(p0 + 2 * HID_DIM + kbase);
        uint4 a3 = *(const uint4*)(p0 + 3 * HID_DIM + kbase);
        uint4 c0 = *(const uint4*)(p1 + 0 * HID_DIM + kbase);
        uint4 c1 = *(const uint4*)(p1 + 1 * HID_DIM + kbase);
        uint4 c2 = *(const uint4*)(p1 + 2 * HID_DIM + kbase);
        uint4 c3 = *(const uint4*)(p1 + 3 * HID_DIM + kbase);
        // pin: all 12 loads issue before any compute (see r15 note above)
        __builtin_amdgcn_sched_barrier(0);

        int wb_i = kbase * 64 + j;
        float wR_0 = root2[wb_i], wR_1 = root2[wb_i + 64], wR_2 = root2[wb_i + 128], wR_3 = root2[wb_i + 192];
        float wR_4 = root2[wb_i + 256], wR_5 = root2[wb_i + 320], wR_6 = root2[wb_i + 384], wR_7 = root2[wb_i + 448];
        float wA_0 = w0[wb_i], wA_1 = w0[wb_i + 64], wA_2 = w0[wb_i + 128], wA_3 = w0[wb_i + 192];
        float wA_4 = w0[wb_i + 256], wA_5 = w0[wb_i + 320], wA_6 = w0[wb_i + 384], wA_7 = w0[wb_i + 448];
        float wB_0 = w1s[wb_i], wB_1 = w1s[wb_i + 64], wB_2 = w1s[wb_i + 128], wB_3 = w1s[wb_i + 192];
        float wB_4 = w1s[wb_i + 256], wB_5 = w1s[wb_i + 320], wB_6 = w1s[wb_i + 384], wB_7 = w1s[wb_i + 448];

        BACC8(accR0, s0, wR_)
        BACC8(accR1, s1, wR_)
        BACC8(accR2, s2, wR_)
        BACC8(accR3, s3, wR_)
        BACC8(acc00, a0, wA_)
        BACC8(acc01, a1, wA_)
        BACC8(acc02, a2, wA_)
        BACC8(acc03, a3, wA_)
        BACC8(acc10, c0, wB_)
        BACC8(acc11, c1, wB_)
        BACC8(acc12, c2, wB_)
        BACC8(acc13, c3, wB_)
    }

    float bj  = b2[j];
    float wcj0 = wc[2 * j], wcj1 = wc[2 * j + 1];
    float bc0 = bc[0], bc1 = bc[1];

#define L2_OUT(i, accR, acc0, acc1)                                           \
    {                                                                         \
        int n = n0 + i;                                                       \
        float h2 = fmaxf(accR + bj + acc0 + acc1, 0.0f);                      \
        float v0 = h2 * wcj0;                                                 \
        float v1 = h2 * wcj1;                                                 \
        for (int off = 32; off >= 1; off >>= 1) {                             \
            v0 += __shfl_xor(v0, off);                                        \
            v1 += __shfl_xor(v1, off);                                        \
        }                                                                     \
        if (j == 0) {                                                         \
            out[(size_t)n * 2 + 0] = v0 + bc0;                                \
            out[(size_t)n * 2 + 1] = v1 + bc1;                                \
        }                                                                     \
    }
    L2_OUT(0, accR0, acc00, acc10)
    L2_OUT(1, accR1, acc01, acc11)
    L2_OUT(2, accR2, acc02, acc12)
    L2_OUT(3, accR3, acc03, acc13)
#undef L2_OUT
}

// ============ launch ============

extern "C" void kernel_launch(void* const* d_in, const int* in_sizes, int n_in,
                              void* d_out, int out_size, void* d_ws, size_t ws_size,
                              hipStream_t stream) {
    const float* x     = (const float*)d_in[0];
    const int*   ei    = (const int*)d_in[1];
    const int*   ea    = (const int*)d_in[2];
    const float* W1    = (const float*)d_in[3];
    const float* root1 = (const float*)d_in[4];
    const float* b1    = (const float*)d_in[5];
    const float* W2    = (const float*)d_in[6];
    const float* root2 = (const float*)d_in[7];
    const float* b2    = (const float*)d_in[8];
    const float* Wc    = (const float*)d_in[9];
    const float* bc    = (const float*)d_in[10];
    float* out = (float*)d_out;

    // ws layout (bytes), peak ~69.6 MB (proven budget >= 77.6 MB):
    //   deg    @ 0        : 2N int   (800000)
    //   offs   @ 800000   : 2N int   (800000)
    //   od     @ 1600000  : 2N int2  (1600000)
    //   elist  @ 3200000  : E int    (4000000)
    //   cursor @ 7200000  : 2N int   (800000)
    //   bsum   @ 8000000  : 4096
    //   rd     @ 8004096  : E int    (4000000)
    //   xb     @ 12004096 : N*32 bf16  (6400000)
    //   M1     @ 18404096 : 2N*32 bf16 (12800000)
    //   h1b    @ 31204096 : N*64 bf16  (12800000)
    //   M2     @ 44004096 : 2N*64 bf16 (25600000)
    char* ws = (char*)d_ws;
    int*   deg    = (int*)(ws);
    int*   offs   = (int*)(ws + 800000);
    int2*  od     = (int2*)(ws + 1600000);
    int*   elist  = (int*)(ws + 3200000);
    int*   cursor = (int*)(ws + 7200000);
    int*   bsum   = (int*)(ws + 8000000);
    int*   rd     = (int*)(ws + 8004096);
    unsigned short* xb  = (unsigned short*)(ws + 12004096);
    unsigned short* M1  = (unsigned short*)(ws + 18404096);
    unsigned short* h1b = (unsigned short*)(ws + 31204096);
    unsigned short* M2  = (unsigned short*)(ws + 44004096);

    const int nblk_scan = (N2 + 255) / 256;                            // 782
    const int grid_e    = (N_EDGES + 255) / 256;                       // 3907
    const int grid_cf   = ((N_EDGES + ECHUNK - 1) / ECHUNK) * NRANGE;  // 489*8
    const int grid_n    = N_NODES / 32;                                // 3125

    hipMemsetAsync(deg, 0, (size_t)N2 * 4, stream);
    k_rd<<<grid_e, 256, 0, stream>>>(ei, ea, rd);
    k_xb<<<(N_NODES * IN_DIM / 4 + 255) / 256, 256, 0, stream>>>(x, xb);
    k_count<<<grid_cf, 256, 0, stream>>>(rd, deg);
    k_scan_local<<<nblk_scan, 256, 0, stream>>>(deg, offs, bsum);
    k_scan_blocks<<<1, 64, 0, stream>>>(bsum, nblk_scan);
    k_scan_add<<<nblk_scan, 256, 0, stream>>>(offs, bsum, deg, cursor, od);
    k_fill<<<grid_cf, 256, 0, stream>>>(rd, ei, cursor, elist);

    // layer 1: gather means in x-space (64B rows), then fused GEMM
    k_mean1<<<grid_n, 512, 0, stream>>>(xb, od, elist, M1);
    k_fgemm1<<<grid_n, 512, 0, stream>>>(x, M1, root1, W1, b1, h1b);

    // layer 2: gather means in h1-space, then fused GEMM + classifier
    k_mean2<<<grid_n, 512, 0, stream>>>(h1b, od, elist, M2);
    k_fgemm2<<<grid_n, 512, 0, stream>>>(h1b, M2, root2, W2, b2, Wc, bc, out);
}

// Round 17
// 230.789 us; speedup vs baseline: 1.1774x; 1.1774x over previous
//
#include <hip/hip_runtime.h>

#define N_NODES 100000
#define N_EDGES 1000000
#define IN_DIM 32
#define HID_DIM 64
#define N2 (2 * N_NODES)          // (rel,node) buckets
#define NRANGE 8                  // dst ranges == XCD count
#define RNODES (N_NODES / NRANGE) // 12500
#define ECHUNK 2048               // edges per block-chunk in count/fill

// ============ edge preprocessing: rd[e] = (dst<<1) | rel ============

__global__ __launch_bounds__(256) void k_rd(
    const int* __restrict__ ei, const int* __restrict__ ea,
    int* __restrict__ rd)
{
    int e = blockIdx.x * 256 + threadIdx.x;
    if (e >= N_EDGES) return;
    rd[e] = (ei[N_EDGES + e] << 1) | ea[2 * e + 1];
}

// ============ helpers ============

__device__ __forceinline__ unsigned short f2bf(float f) {
    unsigned u = __float_as_uint(f);
    return (unsigned short)((u + 0x7FFFu + ((u >> 16) & 1u)) >> 16);  // RNE
}

#define ACC4(acc, v, wa, wb, wc_, wd) \
    acc = fmaf((v).x, wa, acc);       \
    acc = fmaf((v).y, wb, acc);       \
    acc = fmaf((v).z, wc_, acc);      \
    acc = fmaf((v).w, wd, acc);

#define MACC4(A, v, m)                \
    A.x = fmaf((v).x, m, A.x);        \
    A.y = fmaf((v).y, m, A.y);        \
    A.z = fmaf((v).z, m, A.z);        \
    A.w = fmaf((v).w, m, A.w);

#define BUNPACK(v_, u) {                           \
    v_.x = __uint_as_float((u).x << 16);           \
    v_.y = __uint_as_float((u).x & 0xFFFF0000u);   \
    v_.z = __uint_as_float((u).y << 16);           \
    v_.w = __uint_as_float((u).y & 0xFFFF0000u);   \
}

#define BMACC4(A, u, m) { float4 v_; BUNPACK(v_, u) MACC4(A, v_, m) }

// ============ CSR build: XCD-local histogram -> scan -> XCD-local fill ============

__global__ __launch_bounds__(256) void k_count(
    const int* __restrict__ rd, int* __restrict__ deg)
{
    int range = blockIdx.x & (NRANGE - 1);
    int chunk = blockIdx.x >> 3;
    int lo = range * RNODES;
    int e0 = chunk * ECHUNK;
    int e1 = min(e0 + ECHUNK, N_EDGES);
    for (int e = e0 + threadIdx.x; e < e1; e += 256) {
        int v = rd[e];
        int dst = v >> 1;
        if ((unsigned)(dst - lo) < (unsigned)RNODES)
            atomicAdd(&deg[(v & 1) * N_NODES + dst], 1);
    }
}

__global__ __launch_bounds__(256) void k_scan_local(
    const int* __restrict__ deg, int* __restrict__ offs, int* __restrict__ bsum)
{
    int t = threadIdx.x;
    int i = blockIdx.x * 256 + t;
    int v = (i < N2) ? deg[i] : 0;
    int lane = t & 63, w = t >> 6;
    int s = v;
#pragma unroll
    for (int off = 1; off < 64; off <<= 1) {
        int u = __shfl_up(s, off);
        if (lane >= off) s += u;
    }
    __shared__ int wsum[4];
    if (lane == 63) wsum[w] = s;
    __syncthreads();
    int add = 0;
    for (int ww = 0; ww < w; ++ww) add += wsum[ww];
    s += add;
    if (i < N2) offs[i] = s - v;
    if (t == 255) bsum[blockIdx.x] = s;
}

__global__ __launch_bounds__(64) void k_scan_blocks(int* __restrict__ bsum, int nblk)
{
    int lane = threadIdx.x;  // single wave
    int carry = 0;
    for (int base = 0; base < nblk; base += 64) {
        int i = base + lane;
        int v = (i < nblk) ? bsum[i] : 0;
        int s = v;
#pragma unroll
        for (int off = 1; off < 64; off <<= 1) {
            int u = __shfl_up(s, off);
            if (lane >= off) s += u;
        }
        if (i < nblk) bsum[i] = carry + s - v;
        carry += __shfl(s, 63);
    }
}

__global__ __launch_bounds__(256) void k_scan_add(
    const int* __restrict__ offs, const int* __restrict__ bsum,
    const int* __restrict__ deg,
    int* __restrict__ cursor, int2* __restrict__ od)
{
    int i = blockIdx.x * 256 + threadIdx.x;
    if (i >= N2) return;
    int o = offs[i] + bsum[i >> 8];
    cursor[i] = o;
    od[i] = make_int2(o, deg[i]);
}

__global__ __launch_bounds__(256) void k_fill(
    const int* __restrict__ rd, const int* __restrict__ ei,
    int* __restrict__ cursor, int* __restrict__ elist)
{
    int range = blockIdx.x & (NRANGE - 1);
    int chunk = blockIdx.x >> 3;
    int lo = range * RNODES;
    int e0 = chunk * ECHUNK;
    int e1 = min(e0 + ECHUNK, N_EDGES);
    for (int e = e0 + threadIdx.x; e < e1; e += 256) {
        int v = rd[e];
        int dst = v >> 1;
        if ((unsigned)(dst - lo) < (unsigned)RNODES) {
            int src = ei[e];
            int pos = atomicAdd(&cursor[(v & 1) * N_NODES + dst], 1);
            elist[pos] = src;
        }
    }
}

// ============ dense GEMM kernels (r12 structure -- empirical best) ============
// r15/r16 lesson [HIP-compiler]: multi-stream fused GEMMs stay latency-bound
// (VGPR pinned at 32, sched_barrier(0) no-op); r12's single-stream GEMM +
// separate gather measured fastest (231 us total). Reverted to r12 with R
// stored bf16 (−51 MB across the 4 hot kernels). kk loops stay
// "#pragma unroll 1" (full unroll spills, rounds 0-2).

__global__ __launch_bounds__(512, 4) void k_gemm1(
    const float* __restrict__ x,      // [N][32] f32
    const float* __restrict__ root1,  // [32][64]
    const float* __restrict__ W1,     // [2][32][64]
    const float* __restrict__ b1,     // [64]
    unsigned short* __restrict__ Rb,  // [N][64] bf16: x@root1 + b1
    unsigned short* __restrict__ Y)   // [2][N][64] bf16: x@W1_r
{
    __shared__ float wR[IN_DIM * HID_DIM];
    __shared__ float w0[IN_DIM * HID_DIM];
    __shared__ float w1s[IN_DIM * HID_DIM];
    int tid = threadIdx.x;
    for (int i = tid; i < IN_DIM * HID_DIM; i += 512) {
        wR[i]  = root1[i];
        w0[i]  = W1[i];
        w1s[i] = W1[IN_DIM * HID_DIM + i];
    }
    __syncthreads();

    int j  = tid & 63;
    int n0 = __builtin_amdgcn_readfirstlane(blockIdx.x * 32 + ((tid >> 6) << 2));
    const float* px = x + (size_t)n0 * IN_DIM;

    float accR0 = 0, accR1 = 0, accR2 = 0, accR3 = 0;
    float acc00 = 0, acc01 = 0, acc02 = 0, acc03 = 0;
    float acc10 = 0, acc11 = 0, acc12 = 0, acc13 = 0;

#pragma unroll 1
    for (int kk = 0; kk < IN_DIM / 4; ++kk) {
        int kbase = kk * 4;
        float4 xv0 = *(const float4*)(px + 0 * IN_DIM + kbase);
        float4 xv1 = *(const float4*)(px + 1 * IN_DIM + kbase);
        float4 xv2 = *(const float4*)(px + 2 * IN_DIM + kbase);
        float4 xv3 = *(const float4*)(px + 3 * IN_DIM + kbase);
        int wb_i = kbase * 64 + j;
        float wRa = wR[wb_i], wRb = wR[wb_i + 64], wRc = wR[wb_i + 128], wRd = wR[wb_i + 192];
        float w0a = w0[wb_i], w0b = w0[wb_i + 64], w0c = w0[wb_i + 128], w0d = w0[wb_i + 192];
        float w1a = w1s[wb_i], w1b = w1s[wb_i + 64], w1c = w1s[wb_i + 128], w1d = w1s[wb_i + 192];

        ACC4(accR0, xv0, wRa, wRb, wRc, wRd)
        ACC4(accR1, xv1, wRa, wRb, wRc, wRd)
        ACC4(accR2, xv2, wRa, wRb, wRc, wRd)
        ACC4(accR3, xv3, wRa, wRb, wRc, wRd)
        ACC4(acc00, xv0, w0a, w0b, w0c, w0d)
        ACC4(acc01, xv1, w0a, w0b, w0c, w0d)
        ACC4(acc02, xv2, w0a, w0b, w0c, w0d)
        ACC4(acc03, xv3, w0a, w0b, w0c, w0d)
        ACC4(acc10, xv0, w1a, w1b, w1c, w1d)
        ACC4(acc11, xv1, w1a, w1b, w1c, w1d)
        ACC4(acc12, xv2, w1a, w1b, w1c, w1d)
        ACC4(acc13, xv3, w1a, w1b, w1c, w1d)
    }

    float bj = b1[j];
    Rb[(size_t)(n0 + 0) * HID_DIM + j] = f2bf(accR0 + bj);
    Rb[(size_t)(n0 + 1) * HID_DIM + j] = f2bf(accR1 + bj);
    Rb[(size_t)(n0 + 2) * HID_DIM + j] = f2bf(accR2 + bj);
    Rb[(size_t)(n0 + 3) * HID_DIM + j] = f2bf(accR3 + bj);
    unsigned short* Y0 = Y;
    unsigned short* Y1 = Y + (size_t)N_NODES * HID_DIM;
    Y0[(size_t)(n0 + 0) * HID_DIM + j] = f2bf(acc00);
    Y0[(size_t)(n0 + 1) * HID_DIM + j] = f2bf(acc01);
    Y0[(size_t)(n0 + 2) * HID_DIM + j] = f2bf(acc02);
    Y0[(size_t)(n0 + 3) * HID_DIM + j] = f2bf(acc03);
    Y1[(size_t)(n0 + 0) * HID_DIM + j] = f2bf(acc10);
    Y1[(size_t)(n0 + 1) * HID_DIM + j] = f2bf(acc11);
    Y1[(size_t)(n0 + 2) * HID_DIM + j] = f2bf(acc12);
    Y1[(size_t)(n0 + 3) * HID_DIM + j] = f2bf(acc13);
}

__global__ __launch_bounds__(512, 4) void k_gemm2(
    const unsigned short* __restrict__ h1b,  // [N][64] bf16
    const float* __restrict__ root2,  // [64][64]
    const float* __restrict__ W2,     // [2][64][64]
    const float* __restrict__ b2,     // [64]
    unsigned short* __restrict__ Rb,  // [N][64] bf16: h1@root2 + b2
    unsigned short* __restrict__ Y)   // [2][N][64] bf16: h1@W2_r
{
    __shared__ float wR[HID_DIM * HID_DIM];
    __shared__ float w0[HID_DIM * HID_DIM];
    __shared__ float w1s[HID_DIM * HID_DIM];
    int tid = threadIdx.x;
    for (int i = tid; i < HID_DIM * HID_DIM; i += 512) {
        wR[i]  = root2[i];
        w0[i]  = W2[i];
        w1s[i] = W2[HID_DIM * HID_DIM + i];
    }
    __syncthreads();

    int j  = tid & 63;
    int n0 = __builtin_amdgcn_readfirstlane(blockIdx.x * 32 + ((tid >> 6) << 2));
    const unsigned short* pb = h1b + (size_t)n0 * HID_DIM;

    float accR0 = 0, accR1 = 0, accR2 = 0, accR3 = 0;
    float acc00 = 0, acc01 = 0, acc02 = 0, acc03 = 0;
    float acc10 = 0, acc11 = 0, acc12 = 0, acc13 = 0;

#pragma unroll 1
    for (int kk = 0; kk < HID_DIM / 4; ++kk) {
        int kbase = kk * 4;
        uint2 u0 = *(const uint2*)(pb + 0 * HID_DIM + kbase);
        uint2 u1 = *(const uint2*)(pb + 1 * HID_DIM + kbase);
        uint2 u2 = *(const uint2*)(pb + 2 * HID_DIM + kbase);
        uint2 u3 = *(const uint2*)(pb + 3 * HID_DIM + kbase);
        float4 xv0, xv1, xv2, xv3;
        BUNPACK(xv0, u0) BUNPACK(xv1, u1) BUNPACK(xv2, u2) BUNPACK(xv3, u3)
        int wb_i = kbase * 64 + j;
        float wRa = wR[wb_i], wRb = wR[wb_i + 64], wRc = wR[wb_i + 128], wRd = wR[wb_i + 192];
        float w0a = w0[wb_i], w0b = w0[wb_i + 64], w0c = w0[wb_i + 128], w0d = w0[wb_i + 192];
        float w1a = w1s[wb_i], w1b = w1s[wb_i + 64], w1c = w1s[wb_i + 128], w1d = w1s[wb_i + 192];

        ACC4(accR0, xv0, wRa, wRb, wRc, wRd)
        ACC4(accR1, xv1, wRa, wRb, wRc, wRd)
        ACC4(accR2, xv2, wRa, wRb, wRc, wRd)
        ACC4(accR3, xv3, wRa, wRb, wRc, wRd)
        ACC4(acc00, xv0, w0a, w0b, w0c, w0d)
        ACC4(acc01, xv1, w0a, w0b, w0c, w0d)
        ACC4(acc02, xv2, w0a, w0b, w0c, w0d)
        ACC4(acc03, xv3, w0a, w0b, w0c, w0d)
        ACC4(acc10, xv0, w1a, w1b, w1c, w1d)
        ACC4(acc11, xv1, w1a, w1b, w1c, w1d)
        ACC4(acc12, xv2, w1a, w1b, w1c, w1d)
        ACC4(acc13, xv3, w1a, w1b, w1c, w1d)
    }

    float bj = b2[j];
    Rb[(size_t)(n0 + 0) * HID_DIM + j] = f2bf(accR0 + bj);
    Rb[(size_t)(n0 + 1) * HID_DIM + j] = f2bf(accR1 + bj);
    Rb[(size_t)(n0 + 2) * HID_DIM + j] = f2bf(accR2 + bj);
    Rb[(size_t)(n0 + 3) * HID_DIM + j] = f2bf(accR3 + bj);
    unsigned short* Y0 = Y;
    unsigned short* Y1 = Y + (size_t)N_NODES * HID_DIM;
    Y0[(size_t)(n0 + 0) * HID_DIM + j] = f2bf(acc00);
    Y0[(size_t)(n0 + 1) * HID_DIM + j] = f2bf(acc01);
    Y0[(size_t)(n0 + 2) * HID_DIM + j] = f2bf(acc02);
    Y0[(size_t)(n0 + 3) * HID_DIM + j] = f2bf(acc03);
    Y1[(size_t)(n0 + 0) * HID_DIM + j] = f2bf(acc10);
    Y1[(size_t)(n0 + 1) * HID_DIM + j] = f2bf(acc11);
    Y1[(size_t)(n0 + 2) * HID_DIM + j] = f2bf(acc12);
    Y1[(size_t)(n0 + 3) * HID_DIM + j] = f2bf(acc13);
}

// ============ gather-sum kernels (r12 structure, Rb bf16) ============

__global__ __launch_bounds__(512, 8) void k_gather1(
    const unsigned short* __restrict__ Y,   // [2][N][64] bf16
    const unsigned short* __restrict__ Rb,  // [N][64] bf16 (incl. b1)
    const int2* __restrict__ od,
    const int* __restrict__ elist,
    unsigned short* __restrict__ h1b)       // [N][64] bf16
{
    int tid = threadIdx.x;
    int lane = tid & 63;
    int wv   = __builtin_amdgcn_readfirstlane(tid >> 6);
    int n0   = __builtin_amdgcn_readfirstlane(blockIdx.x * 32 + wv * 4);

    int sub  = lane >> 4;
    int node = n0 + sub;
    int q    = lane & 15;
    int base = lane & 48;

    const unsigned short* Y0 = Y;
    const unsigned short* Y1 = Y + (size_t)N_NODES * HID_DIM;

    int2 o0 = od[node];
    int2 o1 = od[N_NODES + node];
    int d0 = o0.y, d1 = o1.y;
    int er0 = (q < d0) ? elist[o0.x + q] : 0;
    int er1 = (q < d1) ? elist[o1.x + q] : 0;

    int dm = max(d0, d1);
    dm = max(dm, __shfl_xor(dm, 16));
    dm = max(dm, __shfl_xor(dm, 32));
    int kend = min(dm, 16);

    float4 A0 = make_float4(0.f, 0.f, 0.f, 0.f);
    float4 A1 = make_float4(0.f, 0.f, 0.f, 0.f);
    for (int k = 0; k < kend; ++k) {
        int i0 = __shfl(er0, base + k);
        int i1 = __shfl(er1, base + k);
        uint2 u0 = *(const uint2*)(Y0 + (size_t)i0 * HID_DIM + q * 4);
        uint2 u1 = *(const uint2*)(Y1 + (size_t)i1 * HID_DIM + q * 4);
        float m0 = (k < d0) ? 1.0f : 0.0f;
        float m1 = (k < d1) ? 1.0f : 0.0f;
        BMACC4(A0, u0, m0)
        BMACC4(A1, u1, m1)
    }
    if (dm > 16) {
        for (int k = 16; k < dm; ++k) {
            int i0 = 0, i1 = 0;
            if (k < d0) i0 = elist[o0.x + k];
            if (k < d1) i1 = elist[o1.x + k];
            uint2 u0 = *(const uint2*)(Y0 + (size_t)i0 * HID_DIM + q * 4);
            uint2 u1 = *(const uint2*)(Y1 + (size_t)i1 * HID_DIM + q * 4);
            float m0 = (k < d0) ? 1.0f : 0.0f;
            float m1 = (k < d1) ? 1.0f : 0.0f;
            BMACC4(A0, u0, m0)
            BMACC4(A1, u1, m1)
        }
    }
    float i0v = 1.0f / fmaxf((float)d0, 1.0f);
    float i1v = 1.0f / fmaxf((float)d1, 1.0f);
    uint2 ru = *(const uint2*)(Rb + (size_t)node * HID_DIM + q * 4);
    float4 Rq; BUNPACK(Rq, ru)
    ushort4 o;
    o.x = f2bf(fmaxf(Rq.x + A0.x * i0v + A1.x * i1v, 0.0f));
    o.y = f2bf(fmaxf(Rq.y + A0.y * i0v + A1.y * i1v, 0.0f));
    o.z = f2bf(fmaxf(Rq.z + A0.z * i0v + A1.z * i1v, 0.0f));
    o.w = f2bf(fmaxf(Rq.w + A0.w * i0v + A1.w * i1v, 0.0f));
    *(ushort4*)(h1b + (size_t)node * HID_DIM + q * 4) = o;
}

__global__ __launch_bounds__(512, 8) void k_gather2(
    const unsigned short* __restrict__ Y,   // [2][N][64] bf16
    const unsigned short* __restrict__ Rb,  // [N][64] bf16 (incl. b2)
    const int2* __restrict__ od,
    const int* __restrict__ elist,
    const float* __restrict__ Wc,           // [64][2]
    const float* __restrict__ bc,           // [2]
    float* __restrict__ out)                // [N][2]
{
    int tid = threadIdx.x;
    int lane = tid & 63;
    int wv   = __builtin_amdgcn_readfirstlane(tid >> 6);
    int n0   = __builtin_amdgcn_readfirstlane(blockIdx.x * 32 + wv * 4);

    int sub  = lane >> 4;
    int node = n0 + sub;
    int q    = lane & 15;
    int base = lane & 48;

    const unsigned short* Y0 = Y;
    const unsigned short* Y1 = Y + (size_t)N_NODES * HID_DIM;

    int2 o0 = od[node];
    int2 o1 = od[N_NODES + node];
    int d0 = o0.y, d1 = o1.y;
    int er0 = (q < d0) ? elist[o0.x + q] : 0;
    int er1 = (q < d1) ? elist[o1.x + q] : 0;

    int dm = max(d0, d1);
    dm = max(dm, __shfl_xor(dm, 16));
    dm = max(dm, __shfl_xor(dm, 32));
    int kend = min(dm, 16);

    float4 A0 = make_float4(0.f, 0.f, 0.f, 0.f);
    float4 A1 = make_float4(0.f, 0.f, 0.f, 0.f);
    for (int k = 0; k < kend; ++k) {
        int i0 = __shfl(er0, base + k);
        int i1 = __shfl(er1, base + k);
        uint2 u0 = *(const uint2*)(Y0 + (size_t)i0 * HID_DIM + q * 4);
        uint2 u1 = *(const uint2*)(Y1 + (size_t)i1 * HID_DIM + q * 4);
        float m0 = (k < d0) ? 1.0f : 0.0f;
        float m1 = (k < d1) ? 1.0f : 0.0f;
        BMACC4(A0, u0, m0)
        BMACC4(A1, u1, m1)
    }
    if (dm > 16) {
        for (int k = 16; k < dm; ++k) {
            int i0 = 0, i1 = 0;
            if (k < d0) i0 = elist[o0.x + k];
            if (k < d1) i1 = elist[o1.x + k];
            uint2 u0 = *(const uint2*)(Y0 + (size_t)i0 * HID_DIM + q * 4);
            uint2 u1 = *(const uint2*)(Y1 + (size_t)i1 * HID_DIM + q * 4);
            float m0 = (k < d0) ? 1.0f : 0.0f;
            float m1 = (k < d1) ? 1.0f : 0.0f;
            BMACC4(A0, u0, m0)
            BMACC4(A1, u1, m1)
        }
    }
    float i0v = 1.0f / fmaxf((float)d0, 1.0f);
    float i1v = 1.0f / fmaxf((float)d1, 1.0f);
    uint2 ru = *(const uint2*)(Rb + (size_t)node * HID_DIM + q * 4);
    float4 Rq; BUNPACK(Rq, ru)
    float4 h2;
    h2.x = fmaxf(Rq.x + A0.x * i0v + A1.x * i1v, 0.0f);
    h2.y = fmaxf(Rq.y + A0.y * i0v + A1.y * i1v, 0.0f);
    h2.z = fmaxf(Rq.z + A0.z * i0v + A1.z * i1v, 0.0f);
    h2.w = fmaxf(Rq.w + A0.w * i0v + A1.w * i1v, 0.0f);

    float4 wcA = *(const float4*)(Wc + 8 * q);
    float4 wcB = *(const float4*)(Wc + 8 * q + 4);
    float v0 = h2.x * wcA.x + h2.y * wcA.z + h2.z * wcB.x + h2.w * wcB.z;
    float v1 = h2.x * wcA.y + h2.y * wcA.w + h2.z * wcB.y + h2.w * wcB.w;
#pragma unroll
    for (int off = 1; off <= 8; off <<= 1) {
        v0 += __shfl_xor(v0, off);
        v1 += __shfl_xor(v1, off);
    }
    if (q == 0) {
        out[(size_t)node * 2 + 0] = v0 + bc[0];
        out[(size_t)node * 2 + 1] = v1 + bc[1];
    }
}

// ============ launch ============

extern "C" void kernel_launch(void* const* d_in, const int* in_sizes, int n_in,
                              void* d_out, int out_size, void* d_ws, size_t ws_size,
                              hipStream_t stream) {
    const float* x     = (const float*)d_in[0];
    const int*   ei    = (const int*)d_in[1];
    const int*   ea    = (const int*)d_in[2];
    const float* W1    = (const float*)d_in[3];
    const float* root1 = (const float*)d_in[4];
    const float* b1    = (const float*)d_in[5];
    const float* W2    = (const float*)d_in[6];
    const float* root2 = (const float*)d_in[7];
    const float* b2    = (const float*)d_in[8];
    const float* Wc    = (const float*)d_in[9];
    const float* bc    = (const float*)d_in[10];
    float* out = (float*)d_out;

    // ws layout (bytes), peak ~63.2 MB (proven budget >= 77.6 MB):
    //   deg    @ 0        : 2N int   (800000)
    //   offs   @ 800000   : 2N int   (800000)
    //   od     @ 1600000  : 2N int2  (1600000)
    //   elist  @ 3200000  : E int    (4000000)
    //   cursor @ 7200000  : 2N int   (800000)
    //   bsum   @ 8000000  : 4096
    //   rd     @ 8004096  : E int    (4000000)
    //   Y      @ 12004096 : 2N*64 bf16 (25600000)   reused by both layers
    //   Rb     @ 37604096 : N*64 bf16  (12800000)   reused by both layers
    //   h1b    @ 50404096 : N*64 bf16  (12800000)
    char* ws = (char*)d_ws;
    int*   deg    = (int*)(ws);
    int*   offs   = (int*)(ws + 800000);
    int2*  od     = (int2*)(ws + 1600000);
    int*   elist  = (int*)(ws + 3200000);
    int*   cursor = (int*)(ws + 7200000);
    int*   bsum   = (int*)(ws + 8000000);
    int*   rd     = (int*)(ws + 8004096);
    unsigned short* Y   = (unsigned short*)(ws + 12004096);
    unsigned short* Rb  = (unsigned short*)(ws + 37604096);
    unsigned short* h1b = (unsigned short*)(ws + 50404096);

    const int nblk_scan = (N2 + 255) / 256;                            // 782
    const int grid_e    = (N_EDGES + 255) / 256;                       // 3907
    const int grid_cf   = ((N_EDGES + ECHUNK - 1) / ECHUNK) * NRANGE;  // 489*8
    const int grid_n    = N_NODES / 32;                                // 3125

    hipMemsetAsync(deg, 0, (size_t)N2 * 4, stream);
    k_rd<<<grid_e, 256, 0, stream>>>(ei, ea, rd);
    k_count<<<grid_cf, 256, 0, stream>>>(rd, deg);
    k_scan_local<<<nblk_scan, 256, 0, stream>>>(deg, offs, bsum);
    k_scan_blocks<<<1, 64, 0, stream>>>(bsum, nblk_scan);
    k_scan_add<<<nblk_scan, 256, 0, stream>>>(offs, bsum, deg, cursor, od);
    k_fill<<<grid_cf, 256, 0, stream>>>(rd, ei, cursor, elist);

    // layer 1: transform-then-gather (linearity: mean(x)@W == mean(x@W))
    k_gemm1<<<grid_n, 512, 0, stream>>>(x, root1, W1, b1, Rb, Y);
    k_gather1<<<grid_n, 512, 0, stream>>>(Y, Rb, od, elist, h1b);

    // layer 2 + classifier
    k_gemm2<<<grid_n, 512, 0, stream>>>(h1b, root2, W2, b2, Rb, Y);
    k_gather2<<<grid_n, 512, 0, stream>>>(Y, Rb, od, elist, Wc, bc, out);
}